// Round 14
// baseline (487.028 us; speedup 1.0000x reference)
//
#include <hip/hip_runtime.h>
#include <hip/hip_bf16.h>

typedef __hip_bfloat16 bf16;
typedef __attribute__((ext_vector_type(8))) short short8;   // 8 bf16 = 4 VGPRs
typedef __attribute__((ext_vector_type(4))) short short4v;  // 4 bf16 = 2 VGPRs
typedef __attribute__((ext_vector_type(4))) float f32x4;    // MFMA C/D

#define BB 4
#define NN 2048
#define DD 256
#define HH 8
#define HD 32
#define BN (BB*NN)          // 8192
#define ELEMS (BN*DD)       // 2097152

// ---------------------------------------------------------------------------
// Scratch in module .bss (~25 MB).
// ---------------------------------------------------------------------------
__device__ int g_isf32;
__device__ __attribute__((aligned(256))) unsigned short g_qb [ELEMS]; // [bh][n][d] bf16 (pre-scaled)
__device__ __attribute__((aligned(256))) unsigned short g_kb [ELEMS]; // [bh][n][d] bf16
__device__ __attribute__((aligned(256))) unsigned short g_tA [ELEMS]; // [bh][d][n] bf16
__device__ __attribute__((aligned(256))) unsigned short g_tB [ELEMS]; // [bh][d][n] bf16
__device__ __attribute__((aligned(256))) float          g_acc[ELEMS]; // [b][n][D] f32
__device__ __attribute__((aligned(256))) unsigned short g_wt [4*DD*DD]; // W^T bf16 [mat][n][k]
__device__ __attribute__((aligned(256))) float g_bias[4*DD];
__device__ __attribute__((aligned(256))) float g_cf[HH*4];

__device__ __forceinline__ float b2f(unsigned short u) {
    union { unsigned int i; float f; } c; c.i = ((unsigned int)u) << 16; return c.f;
}
__device__ __forceinline__ unsigned short f2b(float f) {           // safe path
    bf16 h = __float2bfloat16(f);
    return *reinterpret_cast<unsigned short*>(&h);
}
// pack two f32 -> one u32 of two bf16 (RNE).  gfx950 has a 1-instr pk cvt.
#if __has_builtin(__builtin_amdgcn_cvt_pk_bf16_f32)
typedef __attribute__((ext_vector_type(2))) __bf16 bf16x2t;
__device__ __forceinline__ unsigned int pk2(float a, float b) {
    union { bf16x2t v; unsigned int u; } c;
    c.v = __builtin_amdgcn_cvt_pk_bf16_f32(a, b);
    return c.u;
}
#else
__device__ __forceinline__ unsigned int pk2(float a, float b) {
    unsigned int ua = __float_as_uint(a), ub = __float_as_uint(b);
    ua = (ua + 0x7FFFu + ((ua >> 16) & 1u)) >> 16;
    ub = (ub + 0x7FFFu + ((ub >> 16) & 1u)) & 0xFFFF0000u;
    return ua | ub;
}
#endif
__device__ __forceinline__ float ldin(const void* p, int i, int f32m) {
    return f32m ? ((const float*)p)[i] : b2f(((const unsigned short*)p)[i]);
}

// ---------------------------------------------------------------------------
// Kernel 0: dtype probe (unchanged — verified rounds 4-13).
// ---------------------------------------------------------------------------
__global__ __launch_bounds__(256) void probe_kernel(const void* __restrict__ x)
{
    __shared__ int cnt;
    if (threadIdx.x == 0) cnt = 0;
    __syncthreads();
    const unsigned short* u = (const unsigned short*)x;
    int w = 0;
    for (int i = threadIdx.x; i < 1024; i += 256) {
        const int e = (u[2 * i] >> 7) & 0xFF;
        if (e < 100 || e > 140) ++w;
    }
    atomicAdd(&cnt, w);
    __syncthreads();
    if (threadIdx.x == 0) g_isf32 = (cnt > 300) ? 1 : 0;
}

// ---------------------------------------------------------------------------
// Prep: transpose W[k][n] -> g_wt[mat][n][k] bf16; block(0,0) also preps
// biases + coeffs to f32.
// ---------------------------------------------------------------------------
__global__ __launch_bounds__(256) void prep_w_kernel(
    const void* W0, const void* W1, const void* W2, const void* W3,
    const void* bq, const void* bk, const void* bv, const void* bo,
    const void* coeffs)
{
    const int f32m = g_isf32;
    __shared__ unsigned short tile[64][65];
    const int mat = blockIdx.y;
    const void* W = (mat == 0) ? W0 : (mat == 1) ? W1 : (mat == 2) ? W2 : W3;
    const int k0 = (blockIdx.x >> 2) * 64;
    const int n0 = (blockIdx.x & 3) * 64;
    const int t  = threadIdx.x;

    if (blockIdx.x == 0 && blockIdx.y == 0) {
        g_bias[0 * DD + t] = ldin(bq, t, f32m);
        g_bias[1 * DD + t] = ldin(bk, t, f32m);
        g_bias[2 * DD + t] = ldin(bv, t, f32m);
        g_bias[3 * DD + t] = ldin(bo, t, f32m);
        if (t < 32) g_cf[t] = ldin(coeffs, t, f32m);
    }

    #pragma unroll
    for (int it = 0; it < 16; ++it) {
        const int flat = it * 256 + t;
        const int i = flat >> 6, j = flat & 63;
        tile[j][i] = f2b(ldin(W, (k0 + i) * DD + n0 + j, f32m));
    }
    __syncthreads();
    unsigned short* wt = g_wt + mat * DD * DD;
    #pragma unroll
    for (int it = 0; it < 16; ++it) {
        const int flat = it * 256 + t;
        const int nl = flat >> 6, kl = flat & 63;
        wt[(n0 + nl) * DD + k0 + kl] = tile[nl][kl];
    }
}

// ---------------------------------------------------------------------------
// Kernel 1: QKV projection GEMM (unchanged from r10-r13).
// ---------------------------------------------------------------------------
__global__ __launch_bounds__(256) void qkv_gemm_kernel(const void* __restrict__ x)
{
    __shared__ unsigned short xs[64 * 32];
    __shared__ unsigned short wl[64 * 32];
    const int f32m = g_isf32;
    const int t  = threadIdx.x;
    const int w  = t >> 6, l = t & 63, lg = l >> 4, ln = l & 15;
    const int r0 = blockIdx.x * 64;
    const int n0 = blockIdx.y * 64;
    const int mat = blockIdx.z;
    const unsigned short* wt = g_wt + mat * DD * DD;
    const int sr = t >> 2, sc = (t & 3) * 8;

    f32x4 acc[4] = {{0,0,0,0},{0,0,0,0},{0,0,0,0},{0,0,0,0}};

    for (int kc = 0; kc < DD; kc += 32) {
        __syncthreads();
        if (f32m) {
            const float* src = (const float*)x + (size_t)(r0 + sr) * DD + kc + sc;
            const float4 a = *(const float4*)src;
            const float4 b = *(const float4*)(src + 4);
            union { uint4 v; unsigned short s[8]; } o;
            o.s[0]=f2b(a.x); o.s[1]=f2b(a.y); o.s[2]=f2b(a.z); o.s[3]=f2b(a.w);
            o.s[4]=f2b(b.x); o.s[5]=f2b(b.y); o.s[6]=f2b(b.z); o.s[7]=f2b(b.w);
            *(uint4*)(xs + sr * 32 + sc) = o.v;
        } else {
            *(uint4*)(xs + sr * 32 + sc) =
                *(const uint4*)((const unsigned short*)x + (size_t)(r0 + sr) * DD + kc + sc);
        }
        *(uint4*)(wl + sr * 32 + sc) =
            *(const uint4*)(wt + (size_t)(n0 + sr) * DD + kc + sc);
        __syncthreads();
        const short8 af = *(const short8*)(xs + (w * 16 + ln) * 32 + lg * 8);
        #pragma unroll
        for (int s = 0; s < 4; ++s) {
            const short8 bfr = *(const short8*)(wl + (s * 16 + ln) * 32 + lg * 8);
            acc[s] = __builtin_amdgcn_mfma_f32_16x16x32_bf16(af, bfr, acc[s], 0, 0, 0);
        }
    }

    const float QS = 0.17677669529663687f * 1.4426950408889634f; // scale*log2e
    #pragma unroll
    for (int s = 0; s < 4; ++s) {
        const int j = n0 + s * 16 + ln;
        const float bias = g_bias[mat * DD + j];
        const int h = j >> 5, dd = j & 31;
        #pragma unroll
        for (int r = 0; r < 4; ++r) {
            const int rn = r0 + w * 16 + lg * 4 + r;
            const int b = rn >> 11, n = rn & (NN - 1);
            const int bh = b * HH + h;
            const float val = acc[s][r] + bias;
            if (mat == 0) {
                g_qb[((size_t)bh * NN + n) * HD + dd] = f2b(val * QS);
            } else if (mat == 1) {
                g_kb[((size_t)bh * NN + n) * HD + dd] = f2b(val);
            } else {
                g_tA[((size_t)bh * HD + dd) * NN + n] = f2b(val);
                g_acc[(size_t)rn * DD + j] = g_cf[h * 4] * val;
            }
        }
    }
}

// ---------------------------------------------------------------------------
// Kernel 2 (r14): attention pass — OCCUPANCY-focused restructure.
// r13 post-mortem: prefetch was neutral; ~80% of cycles are stalls with only
// 4 waves/SIMD, and occupancy was LDS-capped (34.8 KB/block -> 4 blocks/CU).
// r14: block = 32 queries (2 Q-frags/wave), keys still split 4 ways ->
// osh[4][32][33]+lsh = 17.4 KB -> 8 blocks/CU, and __launch_bounds__(256,8)
// forces VGPR<=64 (r11's loop fit in exactly 64) -> 8 waves/SIMD, 2x the
// latency hiding.  Grid 2048 blocks.  Numerics identical to r11/r13.
// Per strip: S^T = mfma_16x16x32(K,Q) -> exp2 -> pk -> K=16 PV MFMAs direct.
// ---------------------------------------------------------------------------
__global__ __launch_bounds__(256, 8) void attn_pass_kernel(const int kidx, const int dir)
{
    __shared__ float osh[4][32][33];   // [wave][q][d] (+1 pad)  16.9 KB
    __shared__ float lsh[4][32];       //                         0.5 KB

    const unsigned short* __restrict__ tin  = dir ? g_tB : g_tA;
    unsigned short*       __restrict__ tout = dir ? g_tA : g_tB;

    const int tid = threadIdx.x;
    const int w   = tid >> 6;
    const int l   = tid & 63;
    const int lg  = l >> 4;
    const int ln  = l & 15;

    const int bh = blockIdx.x >> 6;    // b*H + h   (grid 32*64)
    const int qt = blockIdx.x & 63;
    const int h  = bh & (HH - 1);
    const int b  = bh >> 3;
    const int q0 = qt * 32;

    short8 qf[2];
    #pragma unroll
    for (int qi = 0; qi < 2; ++qi)
        qf[qi] = *(const short8*)(g_qb +
            ((size_t)bh * NN + q0 + qi * 16 + ln) * HD + lg * 8);

    const unsigned short* kb = g_kb + (size_t)bh * NN * HD;
    const unsigned short* tb = tin  + (size_t)bh * HD * NN;

    f32x4 oacc[2][2];
    #pragma unroll
    for (int qi = 0; qi < 2; ++qi) { oacc[qi][0] = (f32x4){0,0,0,0}; oacc[qi][1] = (f32x4){0,0,0,0}; }
    float lsum[2] = {0.f, 0.f};
    const f32x4 zero = {0.f, 0.f, 0.f, 0.f};

    for (int it = 0; it < 16; ++it) {
        const int k0 = it * 128 + w * 32;   // this wave's 32-key strip
        const short8 kf0 = *(const short8*)(kb + (size_t)(k0 + ln) * HD + lg * 8);
        const short8 kf1 = *(const short8*)(kb + (size_t)(k0 + 16 + ln) * HD + lg * 8);
        short4v tf[2][2];   // [key-chunk][dim-half]
        #pragma unroll
        for (int c = 0; c < 2; ++c)
            #pragma unroll
            for (int hf = 0; hf < 2; ++hf)
                tf[c][hf] = *(const short4v*)(tb +
                    (size_t)(hf * 16 + ln) * NN + k0 + c * 16 + lg * 4);

        #pragma unroll
        for (int qi = 0; qi < 2; ++qi) {
            f32x4 s0 = __builtin_amdgcn_mfma_f32_16x16x32_bf16(kf0, qf[qi], zero, 0, 0, 0);
            f32x4 s1 = __builtin_amdgcn_mfma_f32_16x16x32_bf16(kf1, qf[qi], zero, 0, 0, 0);
            float p[8];
            #pragma unroll
            for (int r = 0; r < 4; ++r) {
                p[r]     = __builtin_amdgcn_exp2f(s0[r]);
                p[4 + r] = __builtin_amdgcn_exp2f(s1[r]);
                lsum[qi] += p[r] + p[4 + r];
            }
            union { unsigned int u[2]; short4v s; } pb0, pb1;
            pb0.u[0] = pk2(p[0], p[1]); pb0.u[1] = pk2(p[2], p[3]);
            pb1.u[0] = pk2(p[4], p[5]); pb1.u[1] = pk2(p[6], p[7]);
            oacc[qi][0] = __builtin_amdgcn_mfma_f32_16x16x16bf16_1k(tf[0][0], pb0.s, oacc[qi][0], 0, 0, 0);
            oacc[qi][1] = __builtin_amdgcn_mfma_f32_16x16x16bf16_1k(tf[0][1], pb0.s, oacc[qi][1], 0, 0, 0);
            oacc[qi][0] = __builtin_amdgcn_mfma_f32_16x16x16bf16_1k(tf[1][0], pb1.s, oacc[qi][0], 0, 0, 0);
            oacc[qi][1] = __builtin_amdgcn_mfma_f32_16x16x16bf16_1k(tf[1][1], pb1.s, oacc[qi][1], 0, 0, 0);
        }
    }

    // lsum: reduce across lg groups (lanes sharing ln)
    #pragma unroll
    for (int qi = 0; qi < 2; ++qi) {
        lsum[qi] += __shfl_xor(lsum[qi], 16, 64);
        lsum[qi] += __shfl_xor(lsum[qi], 32, 64);
    }
    if (lg == 0) {
        #pragma unroll
        for (int qi = 0; qi < 2; ++qi) lsh[w][qi * 16 + ln] = lsum[qi];
    }

    // store O^T wave-partials: row q = qi*16+ln, col d = hf*16+lg*4+r
    #pragma unroll
    for (int qi = 0; qi < 2; ++qi)
        #pragma unroll
        for (int hf = 0; hf < 2; ++hf)
            #pragma unroll
            for (int r = 0; r < 4; ++r)
                osh[w][qi * 16 + ln][hf * 16 + lg * 4 + r] = oacc[qi][hf][r];
    __syncthreads();

    // combine 4 wave-partials; thread t: q = t&31, dims (t>>5)*4 ..+3
    {
        const int q  = tid & 31;
        const int db = (tid >> 5) * 4;
        const float invl = 1.0f / (lsh[0][q] + lsh[1][q] + lsh[2][q] + lsh[3][q]);
        const float ck = g_cf[h * 4 + kidx];
        #pragma unroll
        for (int dd = 0; dd < 4; ++dd) {
            const int d = db + dd;
            const float val = (osh[0][q][d] + osh[1][q][d] +
                               osh[2][q][d] + osh[3][q][d]) * invl;
            tout[((size_t)bh * HD + d) * NN + q0 + q] = f2b(val);
            float* ga = g_acc + ((size_t)(b * NN + q0 + q)) * DD + h * HD + d;
            *ga += ck * val;
        }
    }
}

// ---------------------------------------------------------------------------
// Kernel 3: output projection GEMM (unchanged).
// ---------------------------------------------------------------------------
__global__ __launch_bounds__(256) void out_gemm_kernel(void* __restrict__ out)
{
    __shared__ unsigned short xs[64 * 32];
    __shared__ unsigned short wl[64 * 32];
    const int f32m = g_isf32;
    const int t  = threadIdx.x;
    const int w  = t >> 6, l = t & 63, lg = l >> 4, ln = l & 15;
    const int r0 = blockIdx.x * 64;
    const int n0 = blockIdx.y * 64;
    const unsigned short* wt = g_wt + 3 * DD * DD;
    const int sr = t >> 2, sc = (t & 3) * 8;

    f32x4 acc[4] = {{0,0,0,0},{0,0,0,0},{0,0,0,0},{0,0,0,0}};

    for (int kc = 0; kc < DD; kc += 32) {
        __syncthreads();
        {
            const float* src = g_acc + (size_t)(r0 + sr) * DD + kc + sc;
            const float4 a = *(const float4*)src;
            const float4 b = *(const float4*)(src + 4);
            union { uint4 v; unsigned short s[8]; } o;
            o.s[0]=f2b(a.x); o.s[1]=f2b(a.y); o.s[2]=f2b(a.z); o.s[3]=f2b(a.w);
            o.s[4]=f2b(b.x); o.s[5]=f2b(b.y); o.s[6]=f2b(b.z); o.s[7]=f2b(b.w);
            *(uint4*)(xs + sr * 32 + sc) = o.v;
        }
        *(uint4*)(wl + sr * 32 + sc) =
            *(const uint4*)(wt + (size_t)(n0 + sr) * DD + kc + sc);
        __syncthreads();
        const short8 af = *(const short8*)(xs + (w * 16 + ln) * 32 + lg * 8);
        #pragma unroll
        for (int s = 0; s < 4; ++s) {
            const short8 bfr = *(const short8*)(wl + (s * 16 + ln) * 32 + lg * 8);
            acc[s] = __builtin_amdgcn_mfma_f32_16x16x32_bf16(af, bfr, acc[s], 0, 0, 0);
        }
    }

    #pragma unroll
    for (int s = 0; s < 4; ++s) {
        const int j = n0 + s * 16 + ln;
        const float bias = g_bias[3 * DD + j];
        #pragma unroll
        for (int r = 0; r < 4; ++r) {
            const int rn = r0 + w * 16 + lg * 4 + r;
            const float val = acc[s][r] + bias;
            if (f32m) ((float*)out)[(size_t)rn * DD + j] = val;
            else      ((bf16*)out)[(size_t)rn * DD + j] = __float2bfloat16(val);
        }
    }
}

// ---------------------------------------------------------------------------
extern "C" void kernel_launch(void* const* d_in, const int* in_sizes, int n_in,
                              void* d_out, int out_size, void* d_ws, size_t ws_size,
                              hipStream_t stream)
{
    const void* x      = d_in[0];
    const void* Wq     = d_in[1];
    const void* bq     = d_in[2];
    const void* Wk     = d_in[3];
    const void* bk     = d_in[4];
    const void* Wv     = d_in[5];
    const void* bv     = d_in[6];
    const void* Wo     = d_in[7];
    const void* bo     = d_in[8];
    const void* coeffs = d_in[9];
    (void)d_ws; (void)ws_size; (void)in_sizes; (void)n_in; (void)out_size;

    probe_kernel<<<1, 256, 0, stream>>>(x);

    prep_w_kernel<<<dim3(16, 4), 256, 0, stream>>>(Wq, Wk, Wv, Wo,
                                                   bq, bk, bv, bo, coeffs);

    qkv_gemm_kernel<<<dim3(128, 4, 3), 256, 0, stream>>>(x);

    const int agrid = (BB * HH) * (NN / 32);   // 32 * 64 = 2048 blocks
    attn_pass_kernel<<<agrid, 256, 0, stream>>>(1, 0); // tA -> tB
    attn_pass_kernel<<<agrid, 256, 0, stream>>>(2, 1); // tB -> tA
    attn_pass_kernel<<<agrid, 256, 0, stream>>>(3, 0); // tA -> tB

    out_gemm_kernel<<<dim3(128, 4), 256, 0, stream>>>(d_out);
}

// Round 15
// 241.622 us; speedup vs baseline: 2.0157x; 2.0157x over previous
//
#include <hip/hip_runtime.h>
#include <hip/hip_bf16.h>

typedef __hip_bfloat16 bf16;
typedef __attribute__((ext_vector_type(8))) short short8;   // 8 bf16 = 4 VGPRs
typedef __attribute__((ext_vector_type(4))) short short4v;  // 4 bf16 = 2 VGPRs
typedef __attribute__((ext_vector_type(4))) float f32x4;    // MFMA C/D

#define BB 4
#define NN 2048
#define DD 256
#define HH 8
#define HD 32
#define BN (BB*NN)          // 8192
#define ELEMS (BN*DD)       // 2097152

// ---------------------------------------------------------------------------
// Scratch in module .bss (~25 MB).
// ---------------------------------------------------------------------------
__device__ int g_isf32;
__device__ __attribute__((aligned(256))) unsigned short g_qb [ELEMS]; // [bh][n][d] bf16 (pre-scaled)
__device__ __attribute__((aligned(256))) unsigned short g_kb [ELEMS]; // [bh][n][d] bf16
__device__ __attribute__((aligned(256))) unsigned short g_tA [ELEMS]; // [bh][d][n] bf16
__device__ __attribute__((aligned(256))) unsigned short g_tB [ELEMS]; // [bh][d][n] bf16
__device__ __attribute__((aligned(256))) float          g_acc[ELEMS]; // [b][n][D] f32
__device__ __attribute__((aligned(256))) unsigned short g_wt [4*DD*DD]; // W^T bf16 [mat][n][k]
__device__ __attribute__((aligned(256))) float g_bias[4*DD];
__device__ __attribute__((aligned(256))) float g_cf[HH*4];

__device__ __forceinline__ float b2f(unsigned short u) {
    union { unsigned int i; float f; } c; c.i = ((unsigned int)u) << 16; return c.f;
}
__device__ __forceinline__ unsigned short f2b(float f) {           // safe path
    bf16 h = __float2bfloat16(f);
    return *reinterpret_cast<unsigned short*>(&h);
}
// pack two f32 -> one u32 of two bf16 (RNE).  gfx950 has a 1-instr pk cvt.
#if __has_builtin(__builtin_amdgcn_cvt_pk_bf16_f32)
typedef __attribute__((ext_vector_type(2))) __bf16 bf16x2t;
__device__ __forceinline__ unsigned int pk2(float a, float b) {
    union { bf16x2t v; unsigned int u; } c;
    c.v = __builtin_amdgcn_cvt_pk_bf16_f32(a, b);
    return c.u;
}
#else
__device__ __forceinline__ unsigned int pk2(float a, float b) {
    unsigned int ua = __float_as_uint(a), ub = __float_as_uint(b);
    ua = (ua + 0x7FFFu + ((ua >> 16) & 1u)) >> 16;
    ub = (ub + 0x7FFFu + ((ub >> 16) & 1u)) & 0xFFFF0000u;
    return ua | ub;
}
#endif
__device__ __forceinline__ float ldin(const void* p, int i, int f32m) {
    return f32m ? ((const float*)p)[i] : b2f(((const unsigned short*)p)[i]);
}

// ---------------------------------------------------------------------------
// Kernel 0: dtype probe (unchanged — verified rounds 4-14).
// ---------------------------------------------------------------------------
__global__ __launch_bounds__(256) void probe_kernel(const void* __restrict__ x)
{
    __shared__ int cnt;
    if (threadIdx.x == 0) cnt = 0;
    __syncthreads();
    const unsigned short* u = (const unsigned short*)x;
    int w = 0;
    for (int i = threadIdx.x; i < 1024; i += 256) {
        const int e = (u[2 * i] >> 7) & 0xFF;
        if (e < 100 || e > 140) ++w;
    }
    atomicAdd(&cnt, w);
    __syncthreads();
    if (threadIdx.x == 0) g_isf32 = (cnt > 300) ? 1 : 0;
}

// ---------------------------------------------------------------------------
// Prep: transpose W[k][n] -> g_wt[mat][n][k] bf16; block(0,0) also preps
// biases + coeffs to f32.
// ---------------------------------------------------------------------------
__global__ __launch_bounds__(256) void prep_w_kernel(
    const void* W0, const void* W1, const void* W2, const void* W3,
    const void* bq, const void* bk, const void* bv, const void* bo,
    const void* coeffs)
{
    const int f32m = g_isf32;
    __shared__ unsigned short tile[64][65];
    const int mat = blockIdx.y;
    const void* W = (mat == 0) ? W0 : (mat == 1) ? W1 : (mat == 2) ? W2 : W3;
    const int k0 = (blockIdx.x >> 2) * 64;
    const int n0 = (blockIdx.x & 3) * 64;
    const int t  = threadIdx.x;

    if (blockIdx.x == 0 && blockIdx.y == 0) {
        g_bias[0 * DD + t] = ldin(bq, t, f32m);
        g_bias[1 * DD + t] = ldin(bk, t, f32m);
        g_bias[2 * DD + t] = ldin(bv, t, f32m);
        g_bias[3 * DD + t] = ldin(bo, t, f32m);
        if (t < 32) g_cf[t] = ldin(coeffs, t, f32m);
    }

    #pragma unroll
    for (int it = 0; it < 16; ++it) {
        const int flat = it * 256 + t;
        const int i = flat >> 6, j = flat & 63;
        tile[j][i] = f2b(ldin(W, (k0 + i) * DD + n0 + j, f32m));
    }
    __syncthreads();
    unsigned short* wt = g_wt + mat * DD * DD;
    #pragma unroll
    for (int it = 0; it < 16; ++it) {
        const int flat = it * 256 + t;
        const int nl = flat >> 6, kl = flat & 63;
        wt[(n0 + nl) * DD + k0 + kl] = tile[nl][kl];
    }
}

// ---------------------------------------------------------------------------
// Kernel 1: QKV projection GEMM (unchanged from r10-r14).
// ---------------------------------------------------------------------------
__global__ __launch_bounds__(256) void qkv_gemm_kernel(const void* __restrict__ x)
{
    __shared__ unsigned short xs[64 * 32];
    __shared__ unsigned short wl[64 * 32];
    const int f32m = g_isf32;
    const int t  = threadIdx.x;
    const int w  = t >> 6, l = t & 63, lg = l >> 4, ln = l & 15;
    const int r0 = blockIdx.x * 64;
    const int n0 = blockIdx.y * 64;
    const int mat = blockIdx.z;
    const unsigned short* wt = g_wt + mat * DD * DD;
    const int sr = t >> 2, sc = (t & 3) * 8;

    f32x4 acc[4] = {{0,0,0,0},{0,0,0,0},{0,0,0,0},{0,0,0,0}};

    for (int kc = 0; kc < DD; kc += 32) {
        __syncthreads();
        if (f32m) {
            const float* src = (const float*)x + (size_t)(r0 + sr) * DD + kc + sc;
            const float4 a = *(const float4*)src;
            const float4 b = *(const float4*)(src + 4);
            union { uint4 v; unsigned short s[8]; } o;
            o.s[0]=f2b(a.x); o.s[1]=f2b(a.y); o.s[2]=f2b(a.z); o.s[3]=f2b(a.w);
            o.s[4]=f2b(b.x); o.s[5]=f2b(b.y); o.s[6]=f2b(b.z); o.s[7]=f2b(b.w);
            *(uint4*)(xs + sr * 32 + sc) = o.v;
        } else {
            *(uint4*)(xs + sr * 32 + sc) =
                *(const uint4*)((const unsigned short*)x + (size_t)(r0 + sr) * DD + kc + sc);
        }
        *(uint4*)(wl + sr * 32 + sc) =
            *(const uint4*)(wt + (size_t)(n0 + sr) * DD + kc + sc);
        __syncthreads();
        const short8 af = *(const short8*)(xs + (w * 16 + ln) * 32 + lg * 8);
        #pragma unroll
        for (int s = 0; s < 4; ++s) {
            const short8 bfr = *(const short8*)(wl + (s * 16 + ln) * 32 + lg * 8);
            acc[s] = __builtin_amdgcn_mfma_f32_16x16x32_bf16(af, bfr, acc[s], 0, 0, 0);
        }
    }

    const float QS = 0.17677669529663687f * 1.4426950408889634f; // scale*log2e
    #pragma unroll
    for (int s = 0; s < 4; ++s) {
        const int j = n0 + s * 16 + ln;
        const float bias = g_bias[mat * DD + j];
        const int h = j >> 5, dd = j & 31;
        #pragma unroll
        for (int r = 0; r < 4; ++r) {
            const int rn = r0 + w * 16 + lg * 4 + r;
            const int b = rn >> 11, n = rn & (NN - 1);
            const int bh = b * HH + h;
            const float val = acc[s][r] + bias;
            if (mat == 0) {
                g_qb[((size_t)bh * NN + n) * HD + dd] = f2b(val * QS);
            } else if (mat == 1) {
                g_kb[((size_t)bh * NN + n) * HD + dd] = f2b(val);
            } else {
                g_tA[((size_t)bh * HD + dd) * NN + n] = f2b(val);
                g_acc[(size_t)rn * DD + j] = g_cf[h * 4] * val;
            }
        }
    }
}

// ---------------------------------------------------------------------------
// Kernel 2 (r15): attention pass — r11 main loop VERBATIM (best: 52.6 µs,
// VGPR=64), with the epilogue combine SPLIT INTO TWO DIM-HALVES so osh is
// [4][64][17] f32 (LDS 34.8 -> 18.4 KB).  r14 post-mortem: forcing 8
// waves/SIMD via __launch_bounds__(256,8) made the allocator emit VGPR=32 +
// massive scratch spill (WRITE_SIZE 12->72MB, 138 µs).  r15 gets 8 blocks/CU
// the safe way: VGPR stays 64 naturally (512/64 = 8 waves/SIMD) and LDS
// 18.4 KB x 8 = 147 KB < 160 KB.  No launch-bounds hint.  Numerics
// bit-identical to r11/r13 (f32 partials, same reduction order).
// ---------------------------------------------------------------------------
__global__ void attn_pass_kernel(const int kidx, const int dir)
{
    __shared__ float osh[4][64][17];   // [wave][q][d-half] (+1 pad)  17.4 KB
    __shared__ float lsh[4][64];       //                              1.0 KB

    const unsigned short* __restrict__ tin  = dir ? g_tB : g_tA;
    unsigned short*       __restrict__ tout = dir ? g_tA : g_tB;

    const int tid = threadIdx.x;
    const int w   = tid >> 6;
    const int l   = tid & 63;
    const int lg  = l >> 4;
    const int ln  = l & 15;

    const int bh = blockIdx.x >> 5;    // b*H + h   (grid 32*32)
    const int qt = blockIdx.x & 31;
    const int h  = bh & (HH - 1);
    const int b  = bh >> 3;
    const int q0 = qt * 64;

    short8 qf[4];
    #pragma unroll
    for (int qi = 0; qi < 4; ++qi)
        qf[qi] = *(const short8*)(g_qb +
            ((size_t)bh * NN + q0 + qi * 16 + ln) * HD + lg * 8);

    const unsigned short* kb = g_kb + (size_t)bh * NN * HD;
    const unsigned short* tb = tin  + (size_t)bh * HD * NN;

    f32x4 oacc[4][2];
    #pragma unroll
    for (int qi = 0; qi < 4; ++qi) { oacc[qi][0] = (f32x4){0,0,0,0}; oacc[qi][1] = (f32x4){0,0,0,0}; }
    float lsum[4] = {0.f, 0.f, 0.f, 0.f};
    const f32x4 zero = {0.f, 0.f, 0.f, 0.f};

    for (int it = 0; it < 16; ++it) {
        const int k0 = it * 128 + w * 32;   // this wave's 32-key strip
        const short8 kf0 = *(const short8*)(kb + (size_t)(k0 + ln) * HD + lg * 8);
        const short8 kf1 = *(const short8*)(kb + (size_t)(k0 + 16 + ln) * HD + lg * 8);
        short4v tf[2][2];   // [key-chunk][dim-half]
        #pragma unroll
        for (int c = 0; c < 2; ++c)
            #pragma unroll
            for (int hf = 0; hf < 2; ++hf)
                tf[c][hf] = *(const short4v*)(tb +
                    (size_t)(hf * 16 + ln) * NN + k0 + c * 16 + lg * 4);

        #pragma unroll
        for (int qi = 0; qi < 4; ++qi) {
            f32x4 s0 = __builtin_amdgcn_mfma_f32_16x16x32_bf16(kf0, qf[qi], zero, 0, 0, 0);
            f32x4 s1 = __builtin_amdgcn_mfma_f32_16x16x32_bf16(kf1, qf[qi], zero, 0, 0, 0);
            float p[8];
            #pragma unroll
            for (int r = 0; r < 4; ++r) {
                p[r]     = __builtin_amdgcn_exp2f(s0[r]);
                p[4 + r] = __builtin_amdgcn_exp2f(s1[r]);
                lsum[qi] += p[r] + p[4 + r];
            }
            union { unsigned int u[2]; short4v s; } pb0, pb1;
            pb0.u[0] = pk2(p[0], p[1]); pb0.u[1] = pk2(p[2], p[3]);
            pb1.u[0] = pk2(p[4], p[5]); pb1.u[1] = pk2(p[6], p[7]);
            oacc[qi][0] = __builtin_amdgcn_mfma_f32_16x16x16bf16_1k(tf[0][0], pb0.s, oacc[qi][0], 0, 0, 0);
            oacc[qi][1] = __builtin_amdgcn_mfma_f32_16x16x16bf16_1k(tf[0][1], pb0.s, oacc[qi][1], 0, 0, 0);
            oacc[qi][0] = __builtin_amdgcn_mfma_f32_16x16x16bf16_1k(tf[1][0], pb1.s, oacc[qi][0], 0, 0, 0);
            oacc[qi][1] = __builtin_amdgcn_mfma_f32_16x16x16bf16_1k(tf[1][1], pb1.s, oacc[qi][1], 0, 0, 0);
        }
    }

    // lsum: reduce across lg groups (lanes sharing ln)
    #pragma unroll
    for (int qi = 0; qi < 4; ++qi) {
        lsum[qi] += __shfl_xor(lsum[qi], 16, 64);
        lsum[qi] += __shfl_xor(lsum[qi], 32, 64);
    }
    if (lg == 0) {
        #pragma unroll
        for (int qi = 0; qi < 4; ++qi) lsh[w][qi * 16 + ln] = lsum[qi];
    }

    // ---- two-phase combine through the half-size osh buffer (f32 exact)
    const float ck = g_cf[h * 4 + kidx];
    const int qc = tid & 63;            // combine: this thread's query
    const int dc = (tid >> 6) * 4;      // combine: dim base within half
    #pragma unroll
    for (int hf = 0; hf < 2; ++hf) {
        if (hf) __syncthreads();        // protect osh reuse between halves
        #pragma unroll
        for (int qi = 0; qi < 4; ++qi)
            #pragma unroll
            for (int r = 0; r < 4; ++r)
                osh[w][qi * 16 + ln][lg * 4 + r] = oacc[qi][hf][r];
        __syncthreads();

        const float invl = 1.0f / (lsh[0][qc] + lsh[1][qc] + lsh[2][qc] + lsh[3][qc]);
        #pragma unroll
        for (int dd = 0; dd < 4; ++dd) {
            const int d = dc + dd;             // dim within half
            const int dim = hf * 16 + d;       // global dim
            const float val = (osh[0][qc][d] + osh[1][qc][d] +
                               osh[2][qc][d] + osh[3][qc][d]) * invl;
            tout[((size_t)bh * HD + dim) * NN + q0 + qc] = f2b(val);
            float* ga = g_acc + ((size_t)(b * NN + q0 + qc)) * DD + h * HD + dim;
            *ga += ck * val;
        }
    }
}

// ---------------------------------------------------------------------------
// Kernel 3: output projection GEMM (unchanged).
// ---------------------------------------------------------------------------
__global__ __launch_bounds__(256) void out_gemm_kernel(void* __restrict__ out)
{
    __shared__ unsigned short xs[64 * 32];
    __shared__ unsigned short wl[64 * 32];
    const int f32m = g_isf32;
    const int t  = threadIdx.x;
    const int w  = t >> 6, l = t & 63, lg = l >> 4, ln = l & 15;
    const int r0 = blockIdx.x * 64;
    const int n0 = blockIdx.y * 64;
    const unsigned short* wt = g_wt + 3 * DD * DD;
    const int sr = t >> 2, sc = (t & 3) * 8;

    f32x4 acc[4] = {{0,0,0,0},{0,0,0,0},{0,0,0,0},{0,0,0,0}};

    for (int kc = 0; kc < DD; kc += 32) {
        __syncthreads();
        {
            const float* src = g_acc + (size_t)(r0 + sr) * DD + kc + sc;
            const float4 a = *(const float4*)src;
            const float4 b = *(const float4*)(src + 4);
            union { uint4 v; unsigned short s[8]; } o;
            o.s[0]=f2b(a.x); o.s[1]=f2b(a.y); o.s[2]=f2b(a.z); o.s[3]=f2b(a.w);
            o.s[4]=f2b(b.x); o.s[5]=f2b(b.y); o.s[6]=f2b(b.z); o.s[7]=f2b(b.w);
            *(uint4*)(xs + sr * 32 + sc) = o.v;
        }
        *(uint4*)(wl + sr * 32 + sc) =
            *(const uint4*)(wt + (size_t)(n0 + sr) * DD + kc + sc);
        __syncthreads();
        const short8 af = *(const short8*)(xs + (w * 16 + ln) * 32 + lg * 8);
        #pragma unroll
        for (int s = 0; s < 4; ++s) {
            const short8 bfr = *(const short8*)(wl + (s * 16 + ln) * 32 + lg * 8);
            acc[s] = __builtin_amdgcn_mfma_f32_16x16x32_bf16(af, bfr, acc[s], 0, 0, 0);
        }
    }

    #pragma unroll
    for (int s = 0; s < 4; ++s) {
        const int j = n0 + s * 16 + ln;
        const float bias = g_bias[3 * DD + j];
        #pragma unroll
        for (int r = 0; r < 4; ++r) {
            const int rn = r0 + w * 16 + lg * 4 + r;
            const float val = acc[s][r] + bias;
            if (f32m) ((float*)out)[(size_t)rn * DD + j] = val;
            else      ((bf16*)out)[(size_t)rn * DD + j] = __float2bfloat16(val);
        }
    }
}

// ---------------------------------------------------------------------------
extern "C" void kernel_launch(void* const* d_in, const int* in_sizes, int n_in,
                              void* d_out, int out_size, void* d_ws, size_t ws_size,
                              hipStream_t stream)
{
    const void* x      = d_in[0];
    const void* Wq     = d_in[1];
    const void* bq     = d_in[2];
    const void* Wk     = d_in[3];
    const void* bk     = d_in[4];
    const void* Wv     = d_in[5];
    const void* bv     = d_in[6];
    const void* Wo     = d_in[7];
    const void* bo     = d_in[8];
    const void* coeffs = d_in[9];
    (void)d_ws; (void)ws_size; (void)in_sizes; (void)n_in; (void)out_size;

    probe_kernel<<<1, 256, 0, stream>>>(x);

    prep_w_kernel<<<dim3(16, 4), 256, 0, stream>>>(Wq, Wk, Wv, Wo,
                                                   bq, bk, bv, bo, coeffs);

    qkv_gemm_kernel<<<dim3(128, 4, 3), 256, 0, stream>>>(x);

    const int agrid = (BB * HH) * (NN / 64);   // 32 * 32 = 1024 blocks
    attn_pass_kernel<<<agrid, 256, 0, stream>>>(1, 0); // tA -> tB
    attn_pass_kernel<<<agrid, 256, 0, stream>>>(2, 1); // tB -> tA
    attn_pass_kernel<<<agrid, 256, 0, stream>>>(3, 0); // tA -> tB

    out_gemm_kernel<<<dim3(128, 4), 256, 0, stream>>>(d_out);
}